// Round 6
// baseline (114.751 us; speedup 1.0000x reference)
//
#include <hip/hip_runtime.h>
#include <hip/hip_bf16.h>
#include <cstdint>

#define B_   8
#define C_   128
#define H_   64
#define W_   64
#define NPT  9
#define OC   256
#define K_   (C_*NPT)   // 1152
#define HW   (H_*W_)    // 4096

typedef __attribute__((ext_vector_type(8))) short short8;
typedef __attribute__((ext_vector_type(4))) float f32x4;
typedef __attribute__((ext_vector_type(4))) unsigned int u32x4;

static __device__ __forceinline__ unsigned short f2bf(float f) {
    union { float f; unsigned u; } a; a.f = f;
    unsigned r = a.u + 0x7fffu + ((a.u >> 16) & 1u);   // RNE
    return (unsigned short)(r >> 16);
}
static __device__ __forceinline__ float bf2f(unsigned short u) {
    union { unsigned u; float f; } a; a.u = ((unsigned)u) << 16;
    return a.f;
}

// ---------------- Kernel A: fp32 offset conv, SGPR-resident weights ----------------
// block = (b, row-pair i0), 512 threads = (j, cg); weights via wave-uniform s_load from wT.
__global__ __launch_bounds__(512) void k_offset3(const float* __restrict__ x,
                                                 const float* __restrict__ wT,
                                                 const float* __restrict__ pb,
                                                 float* __restrict__ off) {
    __shared__ float red[8 * 64 * 19];                // 38912 B
    int bid = blockIdx.x;
    int wg = (bid & 7) * 32 + (bid >> 3);             // XCD swizzle: batch per XCD
    int b = wg >> 5;
    int i0 = (wg & 31) * 2;
    int t = threadIdx.x;
    int j = t & 63;
    int cg = t >> 6;
    int cgu = __builtin_amdgcn_readfirstlane(cg);     // SGPR wave id -> scalar weight loads

    const float* xb = x + (size_t)b * C_ * HW;
    float acc[2][18];
#pragma unroll
    for (int p = 0; p < 2; ++p)
#pragma unroll
        for (int o = 0; o < 18; ++o) acc[p][o] = 0.f;

    for (int cc = 0; cc < 16; ++cc) {
        int c = cgu * 16 + cc;
        const float* xc = xb + (size_t)c * HW;
        float xv[4][3];
#pragma unroll
        for (int q = 0; q < 4; ++q) {
            int row = i0 - 1 + q;
            if (row >= 0 && row < H_) {
                const float* xr = xc + row * W_;
                xv[q][1] = xr[j];
                xv[q][0] = (j > 0)  ? xr[j - 1] : 0.f;
                xv[q][2] = (j < 63) ? xr[j + 1] : 0.f;
            } else {
                xv[q][0] = xv[q][1] = xv[q][2] = 0.f;
            }
        }
        const float* wp = wT + (size_t)c * 9 * 18;    // uniform address -> s_load
#pragma unroll
        for (int tap = 0; tap < 9; ++tap) {
            const int kh = tap / 3, kw = tap % 3;
            float w18[18];
            *(f32x4*)(w18 + 0)  = *(const f32x4*)(wp + tap * 18 + 0);
            *(f32x4*)(w18 + 4)  = *(const f32x4*)(wp + tap * 18 + 4);
            *(f32x4*)(w18 + 8)  = *(const f32x4*)(wp + tap * 18 + 8);
            *(f32x4*)(w18 + 12) = *(const f32x4*)(wp + tap * 18 + 12);
            w18[16] = wp[tap * 18 + 16];
            w18[17] = wp[tap * 18 + 17];
#pragma unroll
            for (int p = 0; p < 2; ++p) {
                float xval = xv[p + kh][kw];
#pragma unroll
                for (int o = 0; o < 18; ++o) acc[p][o] += w18[o] * xval;
            }
        }
    }

#pragma unroll
    for (int p = 0; p < 2; ++p) {
        __syncthreads();
#pragma unroll
        for (int o = 0; o < 18; ++o) red[(cg * 64 + j) * 19 + o] = acc[p][o];
        __syncthreads();
        for (int e = t; e < 64 * 18; e += 512) {
            int jj = e / 18, o = e - jj * 18;
            float s = 0.f;
#pragma unroll
            for (int g = 0; g < 8; ++g) s += red[(g * 64 + jj) * 19 + o];
            off[(((size_t)b * 18 + o) * H_ + (i0 + p)) * W_ + jj] = s + pb[o];
        }
    }
}

// ---------------- Kernel WT: transpose p_conv weights -> wT[c][tap][o] f32 ----------------
__global__ __launch_bounds__(256) void k_prepwt(const float* __restrict__ pw,
                                                float* __restrict__ wT) {
    int idx = blockIdx.x * 256 + threadIdx.x;   // < 20736
    int ct = idx / 18;                          // c*9+tap
    int o = idx - ct * 18;
    wT[idx] = pw[o * K_ + ct];
}

// ---------------- Kernel W: fold BN scale into bf16 weights, K reordered k = n*128 + c ----------------
__global__ __launch_bounds__(256) void k_prepw(const float* __restrict__ cw,
                                               const float* __restrict__ gam,
                                               const float* __restrict__ bet,
                                               const float* __restrict__ mu,
                                               const float* __restrict__ var,
                                               __hip_bfloat16* __restrict__ wbf,
                                               float* __restrict__ bias) {
    int idx = blockIdx.x * 256 + threadIdx.x;   // 0 .. 294911
    int oc = idx / K_;
    int r = idx - oc * K_;
    int n = r >> 7;            // point index
    int c = r & 127;           // channel
    float sc = gam[oc] * rsqrtf(var[oc] + 1e-5f);
    wbf[idx] = __float2bfloat16(cw[oc * K_ + c * NPT + n] * sc);
    if (blockIdx.x == 0 && threadIdx.x < OC) {
        int o = threadIdx.x;
        float s = gam[o] * rsqrtf(var[o] + 1e-5f);
        bias[o] = bet[o] - mu[o] * s;
    }
}

// ---------------- Kernel F: fused gather + MFMA GEMM + BN/SiLU ----------------
// block = (b, row i): 64 px, 512 threads (8 waves). Gather into regs, GEMM 64x256xK.
__global__ __launch_bounds__(512) void k_fused(const float* __restrict__ x,
                                               const float* __restrict__ off,
                                               const __hip_bfloat16* __restrict__ wbf,
                                               const float* __restrict__ bias,
                                               float* __restrict__ out) {
    // union: [0,81920) = sx (gather) ; later sA[2]=[0,16384), sB[2]=[16384,81920)
    __shared__ __align__(16) char smem[81920];
    int bid = blockIdx.x;
    int wg = (bid & 7) * 64 + (bid >> 3);             // XCD swizzle: batch per XCD
    int b = wg >> 6;
    int i = wg & 63;
    int tid = threadIdx.x;
    int wv = tid >> 6, lane = tid & 63;
    int j = lane;
    int lrow = lane & 15, lg = lane >> 4;

    // ---- phase 1: stage x rows i-1..i+3 (clamped) as bf16, granule-swizzled ----
    // sx byte = (s*64+col)*256 + ((g ^ (col&15))<<4) + (c&7)*2
    const float* xb = x + (size_t)b * C_ * HW;
#pragma unroll 4
    for (int it = 0; it < 20; ++it) {
        int ch = it * 512 + tid;        // 10240 float4 chunks
        int c4 = ch & 15;
        int c  = (ch >> 4) & 127;
        int s  = ch >> 11;
        int gr = min(63, max(0, i - 1 + s));
        f32x4 v = *(const f32x4*)(xb + (size_t)c * HW + gr * 64 + c4 * 4);
        int g = c >> 3;
        int sub = (c & 7) * 2;
#pragma unroll
        for (int k2 = 0; k2 < 4; ++k2) {
            int col = c4 * 4 + k2;
            *(unsigned short*)(smem + (s * 64 + col) * 256 + (((g ^ (col & 15)) << 4) + sub)) = f2bf(v[k2]);
        }
    }
    __syncthreads();

    // ---- phase 2: gather 18 granules (8 ch each) into registers ----
    const float* offb = off + (size_t)b * 18 * HW + i * 64 + j;
    u32x4 a_reg[18];
#pragma unroll
    for (int kt = 0; kt < 18; ++kt) {
        int idx = kt * 8 + wv;          // global granule id; k = idx*8+e
        int n = idx >> 4;               // wave-uniform
        int c8 = idx & 15;
        float ox = offb[(size_t)n * HW];
        float oy = offb[(size_t)(n + 9) * HW];
        float pxf = (float)(i + n / 3) + ox;
        float pyf = (float)(j + n % 3) + oy;
        float fx = floorf(pxf), fy = floorf(pyf);
        int r0 = max(0, min(63, (int)fx));
        int r1 = max(0, min(63, (int)fx + 1));
        int c0 = max(0, min(63, (int)fy));
        int c1 = max(0, min(63, (int)fy + 1));
        float pxc = fminf(fmaxf(pxf, 0.f), 63.f);
        float pyc = fminf(fmaxf(pyf, 0.f), 63.f);
        float ax = 1.f + ((float)r0 - pxc);
        float bx = 1.f - ((float)r1 - pxc);
        float ay = 1.f + ((float)c0 - pyc);
        float by = 1.f - ((float)c1 - pyc);
        float w00 = ax * ay, w11 = bx * by, w01 = ax * by, w10 = bx * ay;
        int s0 = max(0, min(4, r0 - (i - 1)));
        int s1 = max(0, min(4, r1 - (i - 1)));
        short8 t00 = *(const short8*)(smem + (s0 * 64 + c0) * 256 + ((c8 ^ (c0 & 15)) << 4));
        short8 t11 = *(const short8*)(smem + (s1 * 64 + c1) * 256 + ((c8 ^ (c1 & 15)) << 4));
        short8 t01 = *(const short8*)(smem + (s0 * 64 + c1) * 256 + ((c8 ^ (c1 & 15)) << 4));
        short8 t10 = *(const short8*)(smem + (s1 * 64 + c0) * 256 + ((c8 ^ (c0 & 15)) << 4));
        u32x4 pk;
#pragma unroll
        for (int p2 = 0; p2 < 4; ++p2) {
            unsigned short rr[2];
#pragma unroll
            for (int e = 0; e < 2; ++e) {
                int ei = p2 * 2 + e;
                float v = w00 * bf2f((unsigned short)t00[ei])
                        + w11 * bf2f((unsigned short)t11[ei])
                        + w01 * bf2f((unsigned short)t01[ei])
                        + w10 * bf2f((unsigned short)t10[ei]);
                rr[e] = f2bf(v);
            }
            pk[p2] = (uint32_t)rr[0] | ((uint32_t)rr[1] << 16);
        }
        a_reg[kt] = pk;
    }
    __syncthreads();   // all waves done reading sx before staging overwrites it

    // ---- phase 3: K-loop GEMM. A-tile [8 slots][64 px][16B]; B-tile [256][128B] XOR-swz ----
    const char* Bb = (const char*)wbf;
    auto stage = [&](int buf, int kt, const u32x4& ag) {
        char* bbase = smem + 16384 + buf * 32768;
#pragma unroll
        for (int q = 0; q < 4; ++q) {       // B: 2048 16B chunks
            int ch = q * 512 + tid;
            int row = ch >> 3, slot = ch & 7;
            int srcoff = row * (K_ * 2) + kt * 128 + ((slot * 16) ^ ((row & 7) << 4));
            __builtin_amdgcn_global_load_lds(
                (const __attribute__((address_space(1))) uint32_t*)(Bb + srcoff),
                (__attribute__((address_space(3))) uint32_t*)(bbase + ch * 16), 16, 0, 0);
        }
        // A: this thread's granule for tile kt -> slot wv, row lane (conflict-free)
        *(u32x4*)(smem + buf * 8192 + wv * 1024 + lane * 16) = ag;
    };

    f32x4 zero = {0.f, 0.f, 0.f, 0.f};
    f32x4 acc[4][2];
#pragma unroll
    for (int m = 0; m < 4; ++m)
#pragma unroll
        for (int n = 0; n < 2; ++n) acc[m][n] = zero;

    stage(0, 0, a_reg[0]);
#pragma unroll
    for (int kt = 0; kt < 18; ++kt) {
        if (kt + 1 < 18) stage((kt + 1) & 1, kt + 1, a_reg[kt + 1]);
        __syncthreads();
        const char* sa = smem + (kt & 1) * 8192;
        const char* sb = smem + 16384 + (kt & 1) * 32768;
#pragma unroll
        for (int kk = 0; kk < 2; ++kk) {
            short8 afr[4], bfr[2];
#pragma unroll
            for (int m = 0; m < 4; ++m)
                afr[m] = *(const short8*)(sa + (kk * 4 + lg) * 1024 + (m * 16 + lrow) * 16);
#pragma unroll
            for (int n = 0; n < 2; ++n) {
                int row = wv * 32 + n * 16 + lrow;
                bfr[n] = *(const short8*)(sb + row * 128 + ((kk * 64 + lg * 16) ^ ((row & 7) << 4)));
            }
#pragma unroll
            for (int m = 0; m < 4; ++m)
#pragma unroll
                for (int n = 0; n < 2; ++n)
                    acc[m][n] = __builtin_amdgcn_mfma_f32_16x16x32_bf16(afr[m], bfr[n], acc[m][n], 0, 0, 0);
        }
        __syncthreads();
    }

    // ---- epilogue: bias + SiLU ----
#pragma unroll
    for (int n = 0; n < 2; ++n) {
        int oc = wv * 32 + n * 16 + lrow;
        float bs = bias[oc];
#pragma unroll
        for (int m = 0; m < 4; ++m) {
#pragma unroll
            for (int r = 0; r < 4; ++r) {
                int px = m * 16 + lg * 4 + r;
                float v = acc[m][n][r] + bs;
                float sv = v / (1.f + __expf(-v));
                out[((size_t)b * OC + oc) * HW + i * 64 + px] = sv;
            }
        }
    }
}

extern "C" void kernel_launch(void* const* d_in, const int* in_sizes, int n_in,
                              void* d_out, int out_size, void* d_ws, size_t ws_size,
                              hipStream_t stream) {
    const float* x   = (const float*)d_in[0];
    const float* pw  = (const float*)d_in[1];
    const float* pb  = (const float*)d_in[2];
    const float* cw  = (const float*)d_in[3];
    const float* gam = (const float*)d_in[4];
    const float* bet = (const float*)d_in[5];
    const float* mu  = (const float*)d_in[6];
    const float* var = (const float*)d_in[7];
    float* out = (float*)d_out;

    char* ws = (char*)d_ws;
    float* off           = (float*)ws;                           // 2,359,296 B
    __hip_bfloat16* wbf  = (__hip_bfloat16*)(ws + 2359296);      //   589,824 B
    float* bias          = (float*)(ws + 2949120);               //     1,024 B
    float* wT            = (float*)(ws + 2950144);               //    82,944 B

    hipLaunchKernelGGL(k_prepwt,  dim3(81),   dim3(256), 0, stream, pw, wT);
    hipLaunchKernelGGL(k_offset3, dim3(256),  dim3(512), 0, stream, x, wT, pb, off);
    hipLaunchKernelGGL(k_prepw,   dim3(1152), dim3(256), 0, stream, cw, gam, bet, mu, var, wbf, bias);
    hipLaunchKernelGGL(k_fused,   dim3(512),  dim3(512), 0, stream, x, off, wbf, bias, out);
}